// Round 1
// baseline (130.118 us; speedup 1.0000x reference)
//
#include <hip/hip_runtime.h>
#include <stdint.h>

// Problem constants (from reference):
//   features: [128, 16384, 6] f32; mask_token: [6] f32; seed 1234
//   MASK_RATIO=0.15 -> target_masked = int(16384*0.15) = 2457
//   n_spans = max(1, int(2457/12.5*2)) = 393
constexpr int NB = 128;
constexpr int SEQ = 16384;
constexpr int NF = 6;
constexpr int NSPANS = 393;
constexpr uint32_t TGT = 2457u;
constexpr int ROWF = SEQ * NF;          // 98304 floats per row
constexpr int ROWF4 = ROWF / 4;         // 24576 float4 per row
constexpr int TOT4 = NB * ROWF4;        // 3145728 float4 total
constexpr int COPY_BLOCKS = TOT4 / 3072;             // 1024 copy blocks (3 float4/thread)

// ---- workspace layout (dword offsets) ----
constexpr int FM_OFF = 0;                           // 128*512 final mask bits
constexpr int FM_DW = NB * (SEQ / 32);              // 65536
constexpr size_t WS_BYTES = (size_t)FM_DW * 4;      // 256 KB

typedef float f32x4 __attribute__((ext_vector_type(4)));

struct Keys {
  uint32_t klo0, klo1;     // randint(k_len) child-2 key (span=16 pow2: only lower bits matter)
  uint32_t khi_s0, khi_s1; // randint(k_start) child-1 key -> higher bits
  uint32_t klo_s0, klo_s1; // randint(k_start) child-2 key -> lower bits
  uint32_t kn0, kn1;       // k_noise
};

// JAX threefry2x32 (20 rounds)
__host__ __device__ inline void tf2x32(uint32_t k0, uint32_t k1,
                                       uint32_t x0, uint32_t x1,
                                       uint32_t& o0, uint32_t& o1) {
  uint32_t ks[3] = {k0, k1, k0 ^ k1 ^ 0x1BD11BDAu};
  uint32_t a = x0 + ks[0], b = x1 + ks[1];
  const uint32_t rot[2][4] = {{13u,15u,26u,6u},{17u,29u,16u,24u}};
#pragma unroll
  for (int i = 0; i < 5; ++i) {
    const uint32_t* r = rot[i & 1];
#pragma unroll
    for (int j = 0; j < 4; ++j) {
      a += b;
      b = (b << r[j]) | (b >> (32u - r[j]));
      b ^= a;
    }
    a += ks[(i + 1) % 3];
    b += ks[(i + 2) % 3] + (uint32_t)(i + 1);
  }
  o0 = a; o1 = b;
}

// JAX partitionable random_bits (32-bit): bits[j] = a ^ b, (a,b) = tf(key, (0, j))
__device__ inline uint32_t rbits(uint32_t k0, uint32_t k1, uint32_t j) {
  uint32_t o0, o1;
  tf2x32(k0, k1, 0u, j, o0, o1);
  return o0 ^ o1;
}

// =============== fused kernel: blocks 0..127 = maskgen (R7-validated),
//                 blocks 128..1151 = pure streaming copy out=feat ===============
// Copy has NO dependency on the mask; the dispatcher runs both block types
// concurrently across all 256 CUs, hiding maskgen under the copy's BW time.
// A small fixup kernel afterwards rewrites only masked+valid positions.
//
// R8 change: __launch_bounds__(1024, 8) -> VGPR cap 64 -> 2 blocks/CU, so the
// 128 producer CUs ALSO host a copy block during the ~10us maskgen phase
// (previously those CUs contributed no copy BW until their producer finished).
// Maskgen live state is sr[16] + one ~8-reg threefry chain, so 64 should fit
// without spill; if this round regresses, the diagnosis is scratch spill in
// the maskgen branch and the bound gets reverted.
__global__ __launch_bounds__(1024, 8)
void fused_kernel(const float* __restrict__ feat, float* __restrict__ out,
                  uint32_t* __restrict__ ws, Keys K) {
  __shared__ uint32_t hist[4096];      // 16 KB
  __shared__ uint32_t cov[SEQ / 32];   // 2 KB
  __shared__ uint32_t fm[SEQ / 32];    // 2 KB
  __shared__ uint32_t wsum[16], ssum[16];
  __shared__ int tielist[256];
  __shared__ uint32_t sH, sA, sT, sN;
  __shared__ int tieCnt;

  const int t = threadIdx.x;

  if (blockIdx.x >= (unsigned)NB) {
    // ---------------- copy path: 3 coalesced float4 per thread ----------------
    // Nontemporal stores: out lines are written once and almost never re-read
    // (fixup touches ~1.15% of positions) -> don't occupy L2 with them.
    const uint32_t n = blockIdx.x - NB;          // 0..1023
    const f32x4* f4 = (const f32x4*)feat + (size_t)n * 3072;
    f32x4* o4 = (f32x4*)out + (size_t)n * 3072;
    f32x4 v0 = f4[t];
    f32x4 v1 = f4[t + 1024];
    f32x4 v2 = f4[t + 2048];
    __builtin_nontemporal_store(v0, &o4[t]);
    __builtin_nontemporal_store(v1, &o4[t + 1024]);
    __builtin_nontemporal_store(v2, &o4[t + 2048]);
    return;
  }

  // ---------------- maskgen path (R7-validated, scores in 16 VGPRs) ----------------
  const int lane = t & 63;
  const int wid = t >> 6;
  const uint32_t b = blockIdx.x;

  for (int i = t; i < 4096; i += 1024) hist[i] = 0u;
  if (t < SEQ / 32) cov[t] = 0u;
  if (t == 0) tieCnt = 0;
  __syncthreads();

  // ---- phase 1: spans (one thread per span, LDS atomicOr) ----
  if (t < NSPANS) {
    uint32_t j = b * (uint32_t)NSPANS + (uint32_t)t;
    uint32_t lenb = rbits(K.klo0, K.klo1, j);
    uint32_t len = 5u + (lenb & 15u);
    uint32_t hb = rbits(K.khi_s0, K.khi_s1, j);
    uint32_t lb = rbits(K.klo_s0, K.klo_s1, j);
    const uint32_t span = 16379u;       // 2^32 % 16379 = 400
    uint32_t start = ((hb % span) * 400u + (lb % span)) % span;
    uint32_t end = start + len; if (end > (uint32_t)SEQ) end = SEQ;
    uint32_t w0 = start >> 5, w1 = (end - 1u) >> 5;
    for (uint32_t w = w0; w <= w1; ++w) {
      uint32_t bs = (w == w0) ? (start & 31u) : 0u;
      uint32_t be = (w == w1) ? ((end - 1u) & 31u) : 31u;
      uint32_t n = be - bs + 1u;
      uint32_t m = (n >= 32u) ? 0xFFFFFFFFu : (((1u << n) - 1u) << bs);
      atomicOr(&cov[w], m);
    }
  }
  __syncthreads();

  // ---- phase 2: single threefry pass -> scores in registers + level-1 hist ----
  // NOTE: all loops touching sr[] stay fully unrolled; runtime-indexed
  // ext-vector/arrays demote to scratch (rule #20).
  const uint32_t jb = b << 14;
  uint32_t sr[16];
#pragma unroll
  for (int i = 0; i < 16; ++i) {
    int s = (i << 10) + t;
    uint32_t bits = rbits(K.kn0, K.kn1, jb + (uint32_t)s);
    uint32_t si = (bits >> 9) + (((cov[s >> 5] >> (s & 31)) & 1u) << 23);
    sr[i] = si;
    atomicAdd(&hist[si >> 12], 1u);
  }
  __syncthreads();

  // ---- phase 3: level-1 select via wave-shuffle suffix scan (4 bins/thread) ----
  {
    uint32_t mysum = 0;
#pragma unroll
    for (int i = 0; i < 4; ++i) mysum += hist[t * 4 + i];
    uint32_t v = mysum;
#pragma unroll
    for (int off = 1; off < 64; off <<= 1) {
      uint32_t n = __shfl_down(v, off, 64);
      if (lane + off < 64) v += n;
    }
    if (lane == 0) wsum[wid] = v;   // wave totals
    __syncthreads();
    if (t < 16) {
      uint32_t w = wsum[t];
#pragma unroll
      for (int off = 1; off < 16; off <<= 1) {
        uint32_t n = __shfl_down(w, off, 64);
        if (t + off < 16) w += n;
      }
      ssum[t] = w;                  // inclusive suffix over wave totals
    }
    __syncthreads();
    uint32_t mine = v + (ssum[wid] - wsum[wid]);   // sum of chunks >= mine
    uint32_t above = mine - mysum;                  // strictly above my chunk
    if (above < TGT && TGT <= mine) {
      uint32_t run = above;
      for (int hb = t * 4 + 3; hb >= t * 4; --hb) {
        uint32_t c = hist[hb];
        if (run + c >= TGT) { sH = (uint32_t)hb; sA = run; break; }
        run += c;
      }
    }
  }
  __syncthreads();
  uint32_t H = sH;
  uint32_t targetB = TGT - sA;

  for (int i = t; i < 4096; i += 1024) hist[i] = 0u;
  __syncthreads();

  // ---- phase 4: level-2 histogram from registers ----
#pragma unroll
  for (int i = 0; i < 16; ++i) {
    uint32_t si = sr[i];
    if ((si >> 12) == H) atomicAdd(&hist[si & 4095u], 1u);
  }
  __syncthreads();
  {
    uint32_t mysum = 0;
#pragma unroll
    for (int i = 0; i < 4; ++i) mysum += hist[t * 4 + i];
    uint32_t v = mysum;
#pragma unroll
    for (int off = 1; off < 64; off <<= 1) {
      uint32_t n = __shfl_down(v, off, 64);
      if (lane + off < 64) v += n;
    }
    if (lane == 0) wsum[wid] = v;
    __syncthreads();
    if (t < 16) {
      uint32_t w = wsum[t];
#pragma unroll
      for (int off = 1; off < 16; off <<= 1) {
        uint32_t n = __shfl_down(w, off, 64);
        if (t + off < 16) w += n;
      }
      ssum[t] = w;
    }
    __syncthreads();
    uint32_t mine = v + (ssum[wid] - wsum[wid]);
    uint32_t above = mine - mysum;
    if (above < targetB && targetB <= mine) {
      uint32_t run = above;
      for (int lb = t * 4 + 3; lb >= t * 4; --lb) {
        uint32_t c = hist[lb];
        if (run + c >= targetB) {
          sT = (H << 12) | (uint32_t)lb;
          sN = targetB - run;   // # ties at T accepted (lowest indices first)
          break;
        }
        run += c;
      }
    }
  }
  __syncthreads();
  uint32_t T = sT, need = sN;

  // ---- phase 5: emit bits via ballot from registers; rank ties by index ----
#pragma unroll
  for (int i = 0; i < 16; ++i) {
    int s = (i << 10) + t;
    uint32_t si = sr[i];
    unsigned long long bal = __ballot(si > T);
    if (si == T) {
      int idx = atomicAdd(&tieCnt, 1);
      if (idx < 256) tielist[idx] = s;
    }
    if (lane == 0)       fm[s >> 5] = (uint32_t)bal;
    else if (lane == 32) fm[s >> 5] = (uint32_t)(bal >> 32);
  }
  __syncthreads();
  int tc = tieCnt < 256 ? tieCnt : 256;
  if (t < tc) {
    int s = tielist[t];
    uint32_t rank = 0;
    for (int j = 0; j < tc; ++j) rank += (tielist[j] < s) ? 1u : 0u;
    if (rank < need) atomicOr(&fm[s >> 5], 1u << (s & 31));
  }
  __syncthreads();
  if (t < SEQ / 32) ws[FM_OFF + (b << 9) + t] = fm[t];
}

// =============== fixup: rewrite masked+valid positions with the token ===============
// R8: one thread per 16-bit HALFWORD (131072 threads, 512 blocks) for 2x the
// waves hiding the scattered-load latency; token stores as 3x float2 (24 B is
// always 8-B aligned, p*24 % 8 == 0).
__global__ __launch_bounds__(256)
void fixup_kernel(const float* __restrict__ feat, const float* __restrict__ tok,
                  const uint32_t* __restrict__ ws, float* __restrict__ out) {
  int g = blockIdx.x * 256 + threadIdx.x;       // halfword index, 0..131071
  uint32_t w = ws[FM_OFF + (g >> 1)];
  uint32_t h = (w >> ((g & 1) << 4)) & 0xFFFFu;
  if (!h) return;
  float2 t01 = make_float2(tok[0], tok[1]);
  float2 t23 = make_float2(tok[2], tok[3]);
  float2 t45 = make_float2(tok[4], tok[5]);
  size_t basePos = (size_t)g * 16;
  while (h) {
    int bit = __ffs(h) - 1;
    h &= h - 1u;
    size_t p = basePos + (size_t)bit;
    float c0 = feat[p * 6];
    if (!(c0 != c0)) {                          // valid = !isnan(channel 0)
      float2* o = (float2*)(out + p * 6);
      o[0] = t01; o[1] = t23; o[2] = t45;
    }
  }
}

// =============== fallback: fully fused single kernel (validated round 2) ===============

__device__ inline uint32_t score_int(const Keys& K, uint32_t b, int s,
                                     const uint32_t* cov) {
  uint32_t j = b * (uint32_t)SEQ + (uint32_t)s;
  uint32_t bits = rbits(K.kn0, K.kn1, j);
  return (bits >> 9) + (((cov[s >> 5] >> (s & 31)) & 1u) << 23);
}

__global__ __launch_bounds__(256)
void mask_kernel(const float* __restrict__ feat, const float* __restrict__ tok,
                 float* __restrict__ out, Keys K) {
  __shared__ uint32_t cov[SEQ / 32];
  __shared__ uint32_t fm[SEQ / 32];
  __shared__ uint32_t hist[4096];
  __shared__ uint32_t part[256];
  __shared__ uint32_t sH, sA, sT, sN;

  const int t = threadIdx.x;
  const uint32_t b = blockIdx.x;

  for (int i = t; i < 4096; i += 256) hist[i] = 0u;
  for (int i = t; i < SEQ / 32; i += 256) cov[i] = 0u;
  __syncthreads();

  for (int i = t; i < NSPANS; i += 256) {
    uint32_t j = b * (uint32_t)NSPANS + (uint32_t)i;
    uint32_t lenb = rbits(K.klo0, K.klo1, j);
    uint32_t len = 5u + (lenb & 15u);
    uint32_t hb = rbits(K.khi_s0, K.khi_s1, j);
    uint32_t lb = rbits(K.klo_s0, K.klo_s1, j);
    const uint32_t span = 16379u;
    uint32_t start = ((hb % span) * 400u + (lb % span)) % span;
    uint32_t end = start + len; if (end > (uint32_t)SEQ) end = SEQ;
    uint32_t w0 = start >> 5, w1 = (end - 1u) >> 5;
    for (uint32_t w = w0; w <= w1; ++w) {
      uint32_t bs = (w == w0) ? (start & 31u) : 0u;
      uint32_t be = (w == w1) ? ((end - 1u) & 31u) : 31u;
      uint32_t n = be - bs + 1u;
      uint32_t m = (n >= 32u) ? 0xFFFFFFFFu : (((1u << n) - 1u) << bs);
      atomicOr(&cov[w], m);
    }
  }
  __syncthreads();

  for (int q = 0; q < 64; ++q) {
    uint32_t si = score_int(K, b, t + (q << 8), cov);
    atomicAdd(&hist[si >> 12], 1u);
  }
  __syncthreads();
  {
    uint32_t sum = 0;
#pragma unroll
    for (int i = 0; i < 16; ++i) sum += hist[t * 16 + i];
    part[t] = sum;
    __syncthreads();
    for (int off = 1; off < 256; off <<= 1) {
      uint32_t v = (t + off < 256) ? part[t + off] : 0u;
      __syncthreads();
      part[t] += v;
      __syncthreads();
    }
    uint32_t above = (t < 255) ? part[t + 1] : 0u;
    uint32_t mine = part[t];
    if (above < TGT && TGT <= mine) {
      uint32_t run = above;
      for (int hb = t * 16 + 15; hb >= t * 16; --hb) {
        uint32_t c = hist[hb];
        if (run + c >= TGT) { sH = (uint32_t)hb; sA = run; break; }
        run += c;
      }
    }
  }
  __syncthreads();
  uint32_t H = sH;
  uint32_t targetB = TGT - sA;

  for (int i = t; i < 4096; i += 256) hist[i] = 0u;
  __syncthreads();
  for (int q = 0; q < 64; ++q) {
    uint32_t si = score_int(K, b, t + (q << 8), cov);
    if ((si >> 12) == H) atomicAdd(&hist[si & 4095u], 1u);
  }
  __syncthreads();
  {
    uint32_t sum = 0;
#pragma unroll
    for (int i = 0; i < 16; ++i) sum += hist[t * 16 + i];
    part[t] = sum;
    __syncthreads();
    for (int off = 1; off < 256; off <<= 1) {
      uint32_t v = (t + off < 256) ? part[t + off] : 0u;
      __syncthreads();
      part[t] += v;
      __syncthreads();
    }
    uint32_t above = (t < 255) ? part[t + 1] : 0u;
    uint32_t mine = part[t];
    if (above < targetB && targetB <= mine) {
      uint32_t run = above;
      for (int lb = t * 16 + 15; lb >= t * 16; --lb) {
        uint32_t c = hist[lb];
        if (run + c >= targetB) { sT = (H << 12) | (uint32_t)lb; sN = targetB - run; break; }
        run += c;
      }
    }
  }
  __syncthreads();
  uint32_t T = sT, need = sN;

  const float* rowf = feat + (size_t)b * ROWF;
  {
    int base = t << 6;
    uint32_t cnt = 0;
    for (int i = 0; i < 64; ++i) cnt += (score_int(K, b, base + i, cov) == T) ? 1u : 0u;
    part[t] = cnt;
    __syncthreads();
    for (int off = 1; off < 256; off <<= 1) {
      uint32_t v = (t >= off) ? part[t - off] : 0u;
      __syncthreads();
      part[t] += v;
      __syncthreads();
    }
    uint32_t r = part[t] - cnt;
    uint32_t w0 = 0, w1 = 0;
    for (int i = 0; i < 64; ++i) {
      int s = base + i;
      uint32_t si = score_int(K, b, s, cov);
      bool tie = (si == T);
      bool a = (si > T) || (tie && r < need);
      r += tie ? 1u : 0u;
      float f0 = rowf[s * 6];
      a = a && !(f0 != f0);
      if (i < 32) w0 |= ((uint32_t)a) << i;
      else        w1 |= ((uint32_t)a) << (i - 32);
    }
    fm[2 * t] = w0;
    fm[2 * t + 1] = w1;
  }
  __syncthreads();

  float tk[NF];
#pragma unroll
  for (int c = 0; c < NF; ++c) tk[c] = tok[c];
  float* rowo = out + (size_t)b * ROWF;
  const float4* rf4 = (const float4*)rowf;
  float4* ro4 = (float4*)rowo;
  for (int q = t; q < ROWF4; q += 256) {
    float4 v = rf4[q];
    float vv[4] = {v.x, v.y, v.z, v.w};
    int e = q * 4;
#pragma unroll
    for (int k = 0; k < 4; ++k) {
      int ee = e + k;
      int p = ee / 6;
      int c = ee - p * 6;
      if ((fm[p >> 5] >> (p & 31)) & 1u) vv[k] = tk[c];
    }
    ro4[q] = make_float4(vv[0], vv[1], vv[2], vv[3]);
  }
}

extern "C" void kernel_launch(void* const* d_in, const int* in_sizes, int n_in,
                              void* d_out, int out_size, void* d_ws, size_t ws_size,
                              hipStream_t stream) {
  const float* feat = (const float*)d_in[0];
  const float* tok = (const float*)d_in[1];
  float* out = (float*)d_out;

  // ---- host-side key derivation (partitionable threefry) ----
  // key(1234) -> (0, 1234); split(key,3) foldlike: child i = tf(key, (0, i))
  uint32_t klen0, klen1, kst0, kst1, kn0, kn1;
  tf2x32(0u, 1234u, 0u, 0u, klen0, klen1);   // k_len
  tf2x32(0u, 1234u, 0u, 1u, kst0, kst1);     // k_start
  tf2x32(0u, 1234u, 0u, 2u, kn0, kn1);       // k_noise
  uint32_t lh0, lh1, ll0, ll1;
  tf2x32(klen0, klen1, 0u, 0u, lh0, lh1);    // unused (span=16 pow2)
  tf2x32(klen0, klen1, 0u, 1u, ll0, ll1);
  (void)lh0; (void)lh1;
  uint32_t sh0, sh1, sl0, sl1;
  tf2x32(kst0, kst1, 0u, 0u, sh0, sh1);
  tf2x32(kst0, kst1, 0u, 1u, sl0, sl1);
  Keys K{ ll0, ll1, sh0, sh1, sl0, sl1, kn0, kn1 };

  if (ws_size >= WS_BYTES) {
    uint32_t* ws = (uint32_t*)d_ws;
    hipLaunchKernelGGL(fused_kernel, dim3(NB + COPY_BLOCKS), dim3(1024), 0, stream,
                       feat, out, ws, K);
    hipLaunchKernelGGL(fixup_kernel, dim3(FM_DW * 2 / 256), dim3(256), 0, stream,
                       feat, tok, ws, out);
  } else {
    hipLaunchKernelGGL(mask_kernel, dim3(NB), dim3(256), 0, stream, feat, tok, out, K);
  }
}

// Round 2
// 115.956 us; speedup vs baseline: 1.1221x; 1.1221x over previous
//
#include <hip/hip_runtime.h>
#include <hip/hip_cooperative_groups.h>
#include <stdint.h>

// Problem constants (from reference):
//   features: [128, 16384, 6] f32; mask_token: [6] f32; seed 1234
//   MASK_RATIO=0.15 -> target_masked = int(16384*0.15) = 2457
//   n_spans = max(1, int(2457/12.5*2)) = 393
constexpr int NB = 128;
constexpr int SEQ = 16384;
constexpr int NF = 6;
constexpr int NSPANS = 393;
constexpr uint32_t TGT = 2457u;
constexpr int ROWF = SEQ * NF;          // 98304 floats per row
constexpr int ROWF4 = ROWF / 4;         // 24576 float4 per row
constexpr int TOT4 = NB * ROWF4;        // 3145728 float4 total
constexpr int COPY_BLOCKS = TOT4 / 3072;             // 1024 copy blocks (3 float4/thread)

// Cooperative grid: 256 blocks. Mask blocks (0..127) copy 9 f4/thread; pure
// copy blocks (128..255) copy 15 f4/thread. 128*9*1024 + 128*15*1024 = TOT4.
constexpr int MASK_PT = 9;
constexpr int STREAM_PT = 15;
constexpr size_t MASK_REGION4 = (size_t)NB * MASK_PT * 1024;   // 1179648

// ---- workspace layout (dword offsets) ----
constexpr int FM_OFF = 0;                           // 128*512 final mask bits
constexpr int FM_DW = NB * (SEQ / 32);              // 65536
constexpr size_t WS_BYTES = (size_t)FM_DW * 4;      // 256 KB

typedef float f32x4 __attribute__((ext_vector_type(4)));

struct Keys {
  uint32_t klo0, klo1;     // randint(k_len) child-2 key (span=16 pow2: only lower bits matter)
  uint32_t khi_s0, khi_s1; // randint(k_start) child-1 key -> higher bits
  uint32_t klo_s0, klo_s1; // randint(k_start) child-2 key -> lower bits
  uint32_t kn0, kn1;       // k_noise
};

// JAX threefry2x32 (20 rounds)
__host__ __device__ inline void tf2x32(uint32_t k0, uint32_t k1,
                                       uint32_t x0, uint32_t x1,
                                       uint32_t& o0, uint32_t& o1) {
  uint32_t ks[3] = {k0, k1, k0 ^ k1 ^ 0x1BD11BDAu};
  uint32_t a = x0 + ks[0], b = x1 + ks[1];
  const uint32_t rot[2][4] = {{13u,15u,26u,6u},{17u,29u,16u,24u}};
#pragma unroll
  for (int i = 0; i < 5; ++i) {
    const uint32_t* r = rot[i & 1];
#pragma unroll
    for (int j = 0; j < 4; ++j) {
      a += b;
      b = (b << r[j]) | (b >> (32u - r[j]));
      b ^= a;
    }
    a += ks[(i + 1) % 3];
    b += ks[(i + 2) % 3] + (uint32_t)(i + 1);
  }
  o0 = a; o1 = b;
}

// JAX partitionable random_bits (32-bit): bits[j] = a ^ b, (a,b) = tf(key, (0, j))
__device__ inline uint32_t rbits(uint32_t k0, uint32_t k1, uint32_t j) {
  uint32_t o0, o1;
  tf2x32(k0, k1, 0u, j, o0, o1);
  return o0 ^ o1;
}

// =============== R9: cooperative single kernel ===============
// Blocks 0..127: maskgen for row b (R7-validated algorithm, fm kept in LDS),
// then a 9-f4/thread copy chunk. Blocks 128..255: 15-f4/thread copy chunk
// (bigger chunk balances the mask blocks' ~7us late start). grid.sync(),
// then each mask block rewrites its own row's masked+valid positions directly
// from its LDS fm — no ws round-trip, no fixup launch.
// __launch_bounds__(1024,4): 16-wave block at 4 waves/EU = exactly 1 block/CU
// -> VGPR cap 128 (maskgen fits; R1 showed cap 64->32 spills catastrophically).
__global__ __launch_bounds__(1024, 4)
void coop_kernel(const float* __restrict__ feat, const float* __restrict__ tok,
                 float* __restrict__ out, Keys K) {
  __shared__ uint32_t hist[4096];      // 16 KB
  __shared__ uint32_t cov[SEQ / 32];   // 2 KB
  __shared__ uint32_t fm[SEQ / 32];    // 2 KB
  __shared__ uint32_t wsum[16], ssum[16];
  __shared__ int tielist[256];
  __shared__ uint32_t sH, sA, sT, sN;
  __shared__ int tieCnt;

  const int t = threadIdx.x;
  const int lane = t & 63;
  const int wid = t >> 6;
  const uint32_t bid = blockIdx.x;

  if (bid < (uint32_t)NB) {
    // ---------------- maskgen (scores live in 16 VGPRs) ----------------
    const uint32_t b = bid;

    for (int i = t; i < 4096; i += 1024) hist[i] = 0u;
    if (t < SEQ / 32) cov[t] = 0u;
    if (t == 0) tieCnt = 0;
    __syncthreads();

    // ---- phase 1: spans (one thread per span, LDS atomicOr) ----
    if (t < NSPANS) {
      uint32_t j = b * (uint32_t)NSPANS + (uint32_t)t;
      uint32_t lenb = rbits(K.klo0, K.klo1, j);
      uint32_t len = 5u + (lenb & 15u);
      uint32_t hb = rbits(K.khi_s0, K.khi_s1, j);
      uint32_t lb = rbits(K.klo_s0, K.klo_s1, j);
      const uint32_t span = 16379u;       // 2^32 % 16379 = 400
      uint32_t start = ((hb % span) * 400u + (lb % span)) % span;
      uint32_t end = start + len; if (end > (uint32_t)SEQ) end = SEQ;
      uint32_t w0 = start >> 5, w1 = (end - 1u) >> 5;
      for (uint32_t w = w0; w <= w1; ++w) {
        uint32_t bs = (w == w0) ? (start & 31u) : 0u;
        uint32_t be = (w == w1) ? ((end - 1u) & 31u) : 31u;
        uint32_t n = be - bs + 1u;
        uint32_t m = (n >= 32u) ? 0xFFFFFFFFu : (((1u << n) - 1u) << bs);
        atomicOr(&cov[w], m);
      }
    }
    __syncthreads();

    // ---- phase 2: threefry pass -> scores in registers + level-1 hist ----
    // All sr[]-touching loops fully unrolled (runtime-indexed regs demote to
    // scratch, rule #20).
    const uint32_t jb = b << 14;
    uint32_t sr[16];
#pragma unroll
    for (int i = 0; i < 16; ++i) {
      int s = (i << 10) + t;
      uint32_t bits = rbits(K.kn0, K.kn1, jb + (uint32_t)s);
      uint32_t si = (bits >> 9) + (((cov[s >> 5] >> (s & 31)) & 1u) << 23);
      sr[i] = si;
      atomicAdd(&hist[si >> 12], 1u);
    }
    __syncthreads();

    // ---- phase 3: level-1 select via wave-shuffle suffix scan ----
    {
      uint32_t mysum = 0;
#pragma unroll
      for (int i = 0; i < 4; ++i) mysum += hist[t * 4 + i];
      uint32_t v = mysum;
#pragma unroll
      for (int off = 1; off < 64; off <<= 1) {
        uint32_t n = __shfl_down(v, off, 64);
        if (lane + off < 64) v += n;
      }
      if (lane == 0) wsum[wid] = v;   // wave totals
      __syncthreads();
      if (t < 16) {
        uint32_t w = wsum[t];
#pragma unroll
        for (int off = 1; off < 16; off <<= 1) {
          uint32_t n = __shfl_down(w, off, 64);
          if (t + off < 16) w += n;
        }
        ssum[t] = w;                  // inclusive suffix over wave totals
      }
      __syncthreads();
      uint32_t mine = v + (ssum[wid] - wsum[wid]);   // sum of chunks >= mine
      uint32_t above = mine - mysum;                  // strictly above my chunk
      if (above < TGT && TGT <= mine) {
        uint32_t run = above;
        for (int hb = t * 4 + 3; hb >= t * 4; --hb) {
          uint32_t c = hist[hb];
          if (run + c >= TGT) { sH = (uint32_t)hb; sA = run; break; }
          run += c;
        }
      }
    }
    __syncthreads();
    uint32_t H = sH;
    uint32_t targetB = TGT - sA;

    for (int i = t; i < 4096; i += 1024) hist[i] = 0u;
    __syncthreads();

    // ---- phase 4: level-2 histogram from registers ----
#pragma unroll
    for (int i = 0; i < 16; ++i) {
      uint32_t si = sr[i];
      if ((si >> 12) == H) atomicAdd(&hist[si & 4095u], 1u);
    }
    __syncthreads();
    {
      uint32_t mysum = 0;
#pragma unroll
      for (int i = 0; i < 4; ++i) mysum += hist[t * 4 + i];
      uint32_t v = mysum;
#pragma unroll
      for (int off = 1; off < 64; off <<= 1) {
        uint32_t n = __shfl_down(v, off, 64);
        if (lane + off < 64) v += n;
      }
      if (lane == 0) wsum[wid] = v;
      __syncthreads();
      if (t < 16) {
        uint32_t w = wsum[t];
#pragma unroll
        for (int off = 1; off < 16; off <<= 1) {
          uint32_t n = __shfl_down(w, off, 64);
          if (t + off < 16) w += n;
        }
        ssum[t] = w;
      }
      __syncthreads();
      uint32_t mine = v + (ssum[wid] - wsum[wid]);
      uint32_t above = mine - mysum;
      if (above < targetB && targetB <= mine) {
        uint32_t run = above;
        for (int lb = t * 4 + 3; lb >= t * 4; --lb) {
          uint32_t c = hist[lb];
          if (run + c >= targetB) {
            sT = (H << 12) | (uint32_t)lb;
            sN = targetB - run;   // # ties at T accepted (lowest indices first)
            break;
          }
          run += c;
        }
      }
    }
    __syncthreads();
    uint32_t T = sT, need = sN;

    // ---- phase 5: emit bits via ballot; rank ties by index ----
#pragma unroll
    for (int i = 0; i < 16; ++i) {
      int s = (i << 10) + t;
      uint32_t si = sr[i];
      unsigned long long bal = __ballot(si > T);
      if (si == T) {
        int idx = atomicAdd(&tieCnt, 1);
        if (idx < 256) tielist[idx] = s;
      }
      if (lane == 0)       fm[s >> 5] = (uint32_t)bal;
      else if (lane == 32) fm[s >> 5] = (uint32_t)(bal >> 32);
    }
    __syncthreads();
    int tc = tieCnt < 256 ? tieCnt : 256;
    if (t < tc) {
      int s = tielist[t];
      uint32_t rank = 0;
      for (int j = 0; j < tc; ++j) rank += (tielist[j] < s) ? 1u : 0u;
      if (rank < need) atomicOr(&fm[s >> 5], 1u << (s & 31));
    }
    __syncthreads();
    // fm[] complete in LDS; no global round-trip needed.
  }

  // ---------------- copy phase (all blocks) ----------------
  {
    if (bid < (uint32_t)NB) {
      const size_t start4 = (size_t)bid * (MASK_PT * 1024);
      const f32x4* f4 = (const f32x4*)feat + start4;
      f32x4* o4 = (f32x4*)out + start4;
      f32x4 v[MASK_PT];
#pragma unroll
      for (int k = 0; k < MASK_PT; ++k) v[k] = f4[t + k * 1024];
#pragma unroll
      for (int k = 0; k < MASK_PT; ++k)
        __builtin_nontemporal_store(v[k], &o4[t + k * 1024]);
    } else {
      const size_t start4 = MASK_REGION4 + (size_t)(bid - NB) * (STREAM_PT * 1024);
      const f32x4* f4 = (const f32x4*)feat + start4;
      f32x4* o4 = (f32x4*)out + start4;
      f32x4 v[STREAM_PT];
#pragma unroll
      for (int k = 0; k < STREAM_PT; ++k) v[k] = f4[t + k * 1024];
#pragma unroll
      for (int k = 0; k < STREAM_PT; ++k)
        __builtin_nontemporal_store(v[k], &o4[t + k * 1024]);
    }
  }

  cooperative_groups::this_grid().sync();

  // ---------------- fixup phase: mask blocks rewrite their own row ----------------
  if (bid < (uint32_t)NB) {
    uint32_t w = fm[t >> 1];
    uint32_t h = (w >> ((t & 1) << 4)) & 0xFFFFu;
    if (h) {
      float2 t01 = make_float2(tok[0], tok[1]);
      float2 t23 = make_float2(tok[2], tok[3]);
      float2 t45 = make_float2(tok[4], tok[5]);
      size_t basePos = (size_t)bid * SEQ + (size_t)(t >> 1) * 32 + (size_t)((t & 1) << 4);
      while (h) {
        int bit = __ffs(h) - 1;
        h &= h - 1u;
        size_t p = basePos + (size_t)bit;
        float c0 = feat[p * 6];
        if (!(c0 != c0)) {                        // valid = !isnan(channel 0)
          float2* o = (float2*)(out + p * 6);
          o[0] = t01; o[1] = t23; o[2] = t45;
        }
      }
    }
  }
}

// =============== fallback A: fused kernel (R0 structure, bounds REVERTED) ===============
__global__ __launch_bounds__(1024)
void fused_kernel(const float* __restrict__ feat, float* __restrict__ out,
                  uint32_t* __restrict__ ws, Keys K) {
  __shared__ uint32_t hist[4096];      // 16 KB
  __shared__ uint32_t cov[SEQ / 32];   // 2 KB
  __shared__ uint32_t fm[SEQ / 32];    // 2 KB
  __shared__ uint32_t wsum[16], ssum[16];
  __shared__ int tielist[256];
  __shared__ uint32_t sH, sA, sT, sN;
  __shared__ int tieCnt;

  const int t = threadIdx.x;

  if (blockIdx.x >= (unsigned)NB) {
    // ---------------- copy path: 3 coalesced float4 per thread ----------------
    const uint32_t n = blockIdx.x - NB;          // 0..1023
    const f32x4* f4 = (const f32x4*)feat + (size_t)n * 3072;
    f32x4* o4 = (f32x4*)out + (size_t)n * 3072;
    f32x4 v0 = f4[t];
    f32x4 v1 = f4[t + 1024];
    f32x4 v2 = f4[t + 2048];
    __builtin_nontemporal_store(v0, &o4[t]);
    __builtin_nontemporal_store(v1, &o4[t + 1024]);
    __builtin_nontemporal_store(v2, &o4[t + 2048]);
    return;
  }

  const int lane = t & 63;
  const int wid = t >> 6;
  const uint32_t b = blockIdx.x;

  for (int i = t; i < 4096; i += 1024) hist[i] = 0u;
  if (t < SEQ / 32) cov[t] = 0u;
  if (t == 0) tieCnt = 0;
  __syncthreads();

  if (t < NSPANS) {
    uint32_t j = b * (uint32_t)NSPANS + (uint32_t)t;
    uint32_t lenb = rbits(K.klo0, K.klo1, j);
    uint32_t len = 5u + (lenb & 15u);
    uint32_t hb = rbits(K.khi_s0, K.khi_s1, j);
    uint32_t lb = rbits(K.klo_s0, K.klo_s1, j);
    const uint32_t span = 16379u;
    uint32_t start = ((hb % span) * 400u + (lb % span)) % span;
    uint32_t end = start + len; if (end > (uint32_t)SEQ) end = SEQ;
    uint32_t w0 = start >> 5, w1 = (end - 1u) >> 5;
    for (uint32_t w = w0; w <= w1; ++w) {
      uint32_t bs = (w == w0) ? (start & 31u) : 0u;
      uint32_t be = (w == w1) ? ((end - 1u) & 31u) : 31u;
      uint32_t n = be - bs + 1u;
      uint32_t m = (n >= 32u) ? 0xFFFFFFFFu : (((1u << n) - 1u) << bs);
      atomicOr(&cov[w], m);
    }
  }
  __syncthreads();

  const uint32_t jb = b << 14;
  uint32_t sr[16];
#pragma unroll
  for (int i = 0; i < 16; ++i) {
    int s = (i << 10) + t;
    uint32_t bits = rbits(K.kn0, K.kn1, jb + (uint32_t)s);
    uint32_t si = (bits >> 9) + (((cov[s >> 5] >> (s & 31)) & 1u) << 23);
    sr[i] = si;
    atomicAdd(&hist[si >> 12], 1u);
  }
  __syncthreads();

  {
    uint32_t mysum = 0;
#pragma unroll
    for (int i = 0; i < 4; ++i) mysum += hist[t * 4 + i];
    uint32_t v = mysum;
#pragma unroll
    for (int off = 1; off < 64; off <<= 1) {
      uint32_t n = __shfl_down(v, off, 64);
      if (lane + off < 64) v += n;
    }
    if (lane == 0) wsum[wid] = v;
    __syncthreads();
    if (t < 16) {
      uint32_t w = wsum[t];
#pragma unroll
      for (int off = 1; off < 16; off <<= 1) {
        uint32_t n = __shfl_down(w, off, 64);
        if (t + off < 16) w += n;
      }
      ssum[t] = w;
    }
    __syncthreads();
    uint32_t mine = v + (ssum[wid] - wsum[wid]);
    uint32_t above = mine - mysum;
    if (above < TGT && TGT <= mine) {
      uint32_t run = above;
      for (int hb = t * 4 + 3; hb >= t * 4; --hb) {
        uint32_t c = hist[hb];
        if (run + c >= TGT) { sH = (uint32_t)hb; sA = run; break; }
        run += c;
      }
    }
  }
  __syncthreads();
  uint32_t H = sH;
  uint32_t targetB = TGT - sA;

  for (int i = t; i < 4096; i += 1024) hist[i] = 0u;
  __syncthreads();

#pragma unroll
  for (int i = 0; i < 16; ++i) {
    uint32_t si = sr[i];
    if ((si >> 12) == H) atomicAdd(&hist[si & 4095u], 1u);
  }
  __syncthreads();
  {
    uint32_t mysum = 0;
#pragma unroll
    for (int i = 0; i < 4; ++i) mysum += hist[t * 4 + i];
    uint32_t v = mysum;
#pragma unroll
    for (int off = 1; off < 64; off <<= 1) {
      uint32_t n = __shfl_down(v, off, 64);
      if (lane + off < 64) v += n;
    }
    if (lane == 0) wsum[wid] = v;
    __syncthreads();
    if (t < 16) {
      uint32_t w = wsum[t];
#pragma unroll
      for (int off = 1; off < 16; off <<= 1) {
        uint32_t n = __shfl_down(w, off, 64);
        if (t + off < 16) w += n;
      }
      ssum[t] = w;
    }
    __syncthreads();
    uint32_t mine = v + (ssum[wid] - wsum[wid]);
    uint32_t above = mine - mysum;
    if (above < targetB && targetB <= mine) {
      uint32_t run = above;
      for (int lb = t * 4 + 3; lb >= t * 4; --lb) {
        uint32_t c = hist[lb];
        if (run + c >= targetB) {
          sT = (H << 12) | (uint32_t)lb;
          sN = targetB - run;
          break;
        }
        run += c;
      }
    }
  }
  __syncthreads();
  uint32_t T = sT, need = sN;

#pragma unroll
  for (int i = 0; i < 16; ++i) {
    int s = (i << 10) + t;
    uint32_t si = sr[i];
    unsigned long long bal = __ballot(si > T);
    if (si == T) {
      int idx = atomicAdd(&tieCnt, 1);
      if (idx < 256) tielist[idx] = s;
    }
    if (lane == 0)       fm[s >> 5] = (uint32_t)bal;
    else if (lane == 32) fm[s >> 5] = (uint32_t)(bal >> 32);
  }
  __syncthreads();
  int tc = tieCnt < 256 ? tieCnt : 256;
  if (t < tc) {
    int s = tielist[t];
    uint32_t rank = 0;
    for (int j = 0; j < tc; ++j) rank += (tielist[j] < s) ? 1u : 0u;
    if (rank < need) atomicOr(&fm[s >> 5], 1u << (s & 31));
  }
  __syncthreads();
  if (t < SEQ / 32) ws[FM_OFF + (b << 9) + t] = fm[t];
}

// =============== fallback A fixup ===============
__global__ __launch_bounds__(256)
void fixup_kernel(const float* __restrict__ feat, const float* __restrict__ tok,
                  const uint32_t* __restrict__ ws, float* __restrict__ out) {
  int g = blockIdx.x * 256 + threadIdx.x;       // halfword index, 0..131071
  uint32_t w = ws[FM_OFF + (g >> 1)];
  uint32_t h = (w >> ((g & 1) << 4)) & 0xFFFFu;
  if (!h) return;
  float2 t01 = make_float2(tok[0], tok[1]);
  float2 t23 = make_float2(tok[2], tok[3]);
  float2 t45 = make_float2(tok[4], tok[5]);
  size_t basePos = (size_t)g * 16;
  while (h) {
    int bit = __ffs(h) - 1;
    h &= h - 1u;
    size_t p = basePos + (size_t)bit;
    float c0 = feat[p * 6];
    if (!(c0 != c0)) {                          // valid = !isnan(channel 0)
      float2* o = (float2*)(out + p * 6);
      o[0] = t01; o[1] = t23; o[2] = t45;
    }
  }
}

// =============== fallback B: fully fused single kernel (validated round 2) ===============

__device__ inline uint32_t score_int(const Keys& K, uint32_t b, int s,
                                     const uint32_t* cov) {
  uint32_t j = b * (uint32_t)SEQ + (uint32_t)s;
  uint32_t bits = rbits(K.kn0, K.kn1, j);
  return (bits >> 9) + (((cov[s >> 5] >> (s & 31)) & 1u) << 23);
}

__global__ __launch_bounds__(256)
void mask_kernel(const float* __restrict__ feat, const float* __restrict__ tok,
                 float* __restrict__ out, Keys K) {
  __shared__ uint32_t cov[SEQ / 32];
  __shared__ uint32_t fm[SEQ / 32];
  __shared__ uint32_t hist[4096];
  __shared__ uint32_t part[256];
  __shared__ uint32_t sH, sA, sT, sN;

  const int t = threadIdx.x;
  const uint32_t b = blockIdx.x;

  for (int i = t; i < 4096; i += 256) hist[i] = 0u;
  for (int i = t; i < SEQ / 32; i += 256) cov[i] = 0u;
  __syncthreads();

  for (int i = t; i < NSPANS; i += 256) {
    uint32_t j = b * (uint32_t)NSPANS + (uint32_t)i;
    uint32_t lenb = rbits(K.klo0, K.klo1, j);
    uint32_t len = 5u + (lenb & 15u);
    uint32_t hb = rbits(K.khi_s0, K.khi_s1, j);
    uint32_t lb = rbits(K.klo_s0, K.klo_s1, j);
    const uint32_t span = 16379u;
    uint32_t start = ((hb % span) * 400u + (lb % span)) % span;
    uint32_t end = start + len; if (end > (uint32_t)SEQ) end = SEQ;
    uint32_t w0 = start >> 5, w1 = (end - 1u) >> 5;
    for (uint32_t w = w0; w <= w1; ++w) {
      uint32_t bs = (w == w0) ? (start & 31u) : 0u;
      uint32_t be = (w == w1) ? ((end - 1u) & 31u) : 31u;
      uint32_t n = be - bs + 1u;
      uint32_t m = (n >= 32u) ? 0xFFFFFFFFu : (((1u << n) - 1u) << bs);
      atomicOr(&cov[w], m);
    }
  }
  __syncthreads();

  for (int q = 0; q < 64; ++q) {
    uint32_t si = score_int(K, b, t + (q << 8), cov);
    atomicAdd(&hist[si >> 12], 1u);
  }
  __syncthreads();
  {
    uint32_t sum = 0;
#pragma unroll
    for (int i = 0; i < 16; ++i) sum += hist[t * 16 + i];
    part[t] = sum;
    __syncthreads();
    for (int off = 1; off < 256; off <<= 1) {
      uint32_t v = (t + off < 256) ? part[t + off] : 0u;
      __syncthreads();
      part[t] += v;
      __syncthreads();
    }
    uint32_t above = (t < 255) ? part[t + 1] : 0u;
    uint32_t mine = part[t];
    if (above < TGT && TGT <= mine) {
      uint32_t run = above;
      for (int hb = t * 16 + 15; hb >= t * 16; --hb) {
        uint32_t c = hist[hb];
        if (run + c >= TGT) { sH = (uint32_t)hb; sA = run; break; }
        run += c;
      }
    }
  }
  __syncthreads();
  uint32_t H = sH;
  uint32_t targetB = TGT - sA;

  for (int i = t; i < 4096; i += 256) hist[i] = 0u;
  __syncthreads();
  for (int q = 0; q < 64; ++q) {
    uint32_t si = score_int(K, b, t + (q << 8), cov);
    if ((si >> 12) == H) atomicAdd(&hist[si & 4095u], 1u);
  }
  __syncthreads();
  {
    uint32_t sum = 0;
#pragma unroll
    for (int i = 0; i < 16; ++i) sum += hist[t * 16 + i];
    part[t] = sum;
    __syncthreads();
    for (int off = 1; off < 256; off <<= 1) {
      uint32_t v = (t + off < 256) ? part[t + off] : 0u;
      __syncthreads();
      part[t] += v;
      __syncthreads();
    }
    uint32_t above = (t < 255) ? part[t + 1] : 0u;
    uint32_t mine = part[t];
    if (above < targetB && targetB <= mine) {
      uint32_t run = above;
      for (int lb = t * 16 + 15; lb >= t * 16; --lb) {
        uint32_t c = hist[lb];
        if (run + c >= targetB) { sT = (H << 12) | (uint32_t)lb; sN = targetB - run; break; }
        run += c;
      }
    }
  }
  __syncthreads();
  uint32_t T = sT, need = sN;

  const float* rowf = feat + (size_t)b * ROWF;
  {
    int base = t << 6;
    uint32_t cnt = 0;
    for (int i = 0; i < 64; ++i) cnt += (score_int(K, b, base + i, cov) == T) ? 1u : 0u;
    part[t] = cnt;
    __syncthreads();
    for (int off = 1; off < 256; off <<= 1) {
      uint32_t v = (t >= off) ? part[t - off] : 0u;
      __syncthreads();
      part[t] += v;
      __syncthreads();
    }
    uint32_t r = part[t] - cnt;
    uint32_t w0 = 0, w1 = 0;
    for (int i = 0; i < 64; ++i) {
      int s = base + i;
      uint32_t si = score_int(K, b, s, cov);
      bool tie = (si == T);
      bool a = (si > T) || (tie && r < need);
      r += tie ? 1u : 0u;
      float f0 = rowf[s * 6];
      a = a && !(f0 != f0);
      if (i < 32) w0 |= ((uint32_t)a) << i;
      else        w1 |= ((uint32_t)a) << (i - 32);
    }
    fm[2 * t] = w0;
    fm[2 * t + 1] = w1;
  }
  __syncthreads();

  float tk[NF];
#pragma unroll
  for (int c = 0; c < NF; ++c) tk[c] = tok[c];
  float* rowo = out + (size_t)b * ROWF;
  const float4* rf4 = (const float4*)rowf;
  float4* ro4 = (float4*)rowo;
  for (int q = t; q < ROWF4; q += 256) {
    float4 v = rf4[q];
    float vv[4] = {v.x, v.y, v.z, v.w};
    int e = q * 4;
#pragma unroll
    for (int k = 0; k < 4; ++k) {
      int ee = e + k;
      int p = ee / 6;
      int c = ee - p * 6;
      if ((fm[p >> 5] >> (p & 31)) & 1u) vv[k] = tk[c];
    }
    ro4[q] = make_float4(vv[0], vv[1], vv[2], vv[3]);
  }
}

extern "C" void kernel_launch(void* const* d_in, const int* in_sizes, int n_in,
                              void* d_out, int out_size, void* d_ws, size_t ws_size,
                              hipStream_t stream) {
  const float* feat = (const float*)d_in[0];
  const float* tok = (const float*)d_in[1];
  float* out = (float*)d_out;

  // ---- host-side key derivation (partitionable threefry) ----
  uint32_t klen0, klen1, kst0, kst1, kn0, kn1;
  tf2x32(0u, 1234u, 0u, 0u, klen0, klen1);   // k_len
  tf2x32(0u, 1234u, 0u, 1u, kst0, kst1);     // k_start
  tf2x32(0u, 1234u, 0u, 2u, kn0, kn1);       // k_noise
  uint32_t lh0, lh1, ll0, ll1;
  tf2x32(klen0, klen1, 0u, 0u, lh0, lh1);    // unused (span=16 pow2)
  tf2x32(klen0, klen1, 0u, 1u, ll0, ll1);
  (void)lh0; (void)lh1;
  uint32_t sh0, sh1, sl0, sl1;
  tf2x32(kst0, kst1, 0u, 0u, sh0, sh1);
  tf2x32(kst0, kst1, 0u, 1u, sl0, sl1);
  Keys K{ ll0, ll1, sh0, sh1, sl0, sl1, kn0, kn1 };

  // ---- cooperative-capability check (host query only, done once) ----
  static int g_coopOk = -1;
  if (g_coopOk < 0) {
    int nb = 0;
    hipError_t qe = hipOccupancyMaxActiveBlocksPerMultiprocessor(&nb, coop_kernel, 1024, 0);
    g_coopOk = (qe == hipSuccess && nb >= 1) ? 1 : 0;
  }

  bool launched = false;
  if (g_coopOk == 1) {
    void* args[] = { (void*)&feat, (void*)&tok, (void*)&out, (void*)&K };
    hipError_t e = hipLaunchCooperativeKernel(coop_kernel, dim3(256), dim3(1024),
                                              args, 0u, stream);
    if (e == hipSuccess) launched = true;
    else g_coopOk = 0;   // don't retry next iteration
  }

  if (!launched) {
    if (ws_size >= WS_BYTES) {
      uint32_t* ws = (uint32_t*)d_ws;
      hipLaunchKernelGGL(fused_kernel, dim3(NB + COPY_BLOCKS), dim3(1024), 0, stream,
                         feat, out, ws, K);
      hipLaunchKernelGGL(fixup_kernel, dim3(FM_DW * 2 / 256), dim3(256), 0, stream,
                         feat, tok, ws, out);
    } else {
      hipLaunchKernelGGL(mask_kernel, dim3(NB), dim3(256), 0, stream, feat, tok, out, K);
    }
  }
}

// Round 3
// 115.129 us; speedup vs baseline: 1.1302x; 1.0072x over previous
//
#include <hip/hip_runtime.h>
#include <stdint.h>

// Problem constants (from reference):
//   features: [128, 16384, 6] f32; mask_token: [6] f32; seed 1234
//   MASK_RATIO=0.15 -> target_masked = int(16384*0.15) = 2457
//   n_spans = max(1, int(2457/12.5*2)) = 393
constexpr int NB = 128;
constexpr int SEQ = 16384;
constexpr int NSPANS = 393;
constexpr uint32_t TGT = 2457u;
constexpr int ROWF = SEQ * 6;           // 98304 floats per row
constexpr int ROWF4 = ROWF / 4;         // 24576 float4 per row
constexpr int HALF4 = ROWF4 / 2;        // 12288 float4 per half-row

typedef float f32x4 __attribute__((ext_vector_type(4)));

struct Keys {
  uint32_t klo0, klo1;     // randint(k_len) child-2 key (span=16 pow2: only lower bits matter)
  uint32_t khi_s0, khi_s1; // randint(k_start) child-1 key -> higher bits
  uint32_t klo_s0, klo_s1; // randint(k_start) child-2 key -> lower bits
  uint32_t kn0, kn1;       // k_noise
};

// JAX threefry2x32 (20 rounds)
__host__ __device__ inline void tf2x32(uint32_t k0, uint32_t k1,
                                       uint32_t x0, uint32_t x1,
                                       uint32_t& o0, uint32_t& o1) {
  uint32_t ks[3] = {k0, k1, k0 ^ k1 ^ 0x1BD11BDAu};
  uint32_t a = x0 + ks[0], b = x1 + ks[1];
  const uint32_t rot[2][4] = {{13u,15u,26u,6u},{17u,29u,16u,24u}};
#pragma unroll
  for (int i = 0; i < 5; ++i) {
    const uint32_t* r = rot[i & 1];
#pragma unroll
    for (int j = 0; j < 4; ++j) {
      a += b;
      b = (b << r[j]) | (b >> (32u - r[j]));
      b ^= a;
    }
    a += ks[(i + 1) % 3];
    b += ks[(i + 2) % 3] + (uint32_t)(i + 1);
  }
  o0 = a; o1 = b;
}

// JAX partitionable random_bits (32-bit): bits[j] = a ^ b, (a,b) = tf(key, (0, j))
__device__ inline uint32_t rbits(uint32_t k0, uint32_t k1, uint32_t j) {
  uint32_t o0, o1;
  tf2x32(k0, k1, 0u, j, o0, o1);
  return o0 ^ o1;
}

// =============== R10: 2-blocks-per-row, redundant maskgen, inline masked copy ===============
// 256 blocks x 1024 threads (1 block/CU). Block bid handles row b = bid>>1,
// half h = bid&1. Both blocks of a row redundantly run the full (validated)
// maskgen -> fm[] in LDS (deterministic threefry => identical), then each
// masked-copies its OWN half-row directly (token select in registers).
// No workspace, no fixup kernel, no grid sync, no scattered 24B rewrites.
// Redundant maskgen is free: it's pure VALU on CUs that would otherwise idle,
// and the memory system is idle during that phase anyway.
__global__ __launch_bounds__(1024)
void rowpair_kernel(const float* __restrict__ feat, const float* __restrict__ tok,
                    float* __restrict__ out, Keys K) {
  __shared__ uint32_t hist[4096];      // 16 KB
  __shared__ uint32_t cov[SEQ / 32];   // 2 KB
  __shared__ uint32_t fm[SEQ / 32];    // 2 KB
  __shared__ uint32_t wsum[16], ssum[16];
  __shared__ int tielist[256];
  __shared__ uint32_t sH, sA, sT, sN;
  __shared__ int tieCnt;

  const int t = threadIdx.x;
  const int lane = t & 63;
  const int wid = t >> 6;
  const uint32_t bid = blockIdx.x;
  const uint32_t b = bid >> 1;         // row
  const int h = (int)(bid & 1u);       // half

  // ---------------- maskgen (R7-validated algorithm, verbatim) ----------------
  for (int i = t; i < 4096; i += 1024) hist[i] = 0u;
  if (t < SEQ / 32) cov[t] = 0u;
  if (t == 0) tieCnt = 0;
  __syncthreads();

  // ---- phase 1: spans (one thread per span, LDS atomicOr) ----
  if (t < NSPANS) {
    uint32_t j = b * (uint32_t)NSPANS + (uint32_t)t;
    uint32_t lenb = rbits(K.klo0, K.klo1, j);
    uint32_t len = 5u + (lenb & 15u);
    uint32_t hb = rbits(K.khi_s0, K.khi_s1, j);
    uint32_t lb = rbits(K.klo_s0, K.klo_s1, j);
    const uint32_t span = 16379u;       // 2^32 % 16379 = 400
    uint32_t start = ((hb % span) * 400u + (lb % span)) % span;
    uint32_t end = start + len; if (end > (uint32_t)SEQ) end = SEQ;
    uint32_t w0 = start >> 5, w1 = (end - 1u) >> 5;
    for (uint32_t w = w0; w <= w1; ++w) {
      uint32_t bs = (w == w0) ? (start & 31u) : 0u;
      uint32_t be = (w == w1) ? ((end - 1u) & 31u) : 31u;
      uint32_t n = be - bs + 1u;
      uint32_t m = (n >= 32u) ? 0xFFFFFFFFu : (((1u << n) - 1u) << bs);
      atomicOr(&cov[w], m);
    }
  }
  __syncthreads();

  // ---- phase 2: threefry pass -> scores in registers + level-1 hist ----
  // All sr[]-touching loops fully unrolled (runtime-indexed regs -> scratch, rule #20).
  const uint32_t jb = b << 14;
  uint32_t sr[16];
#pragma unroll
  for (int i = 0; i < 16; ++i) {
    int s = (i << 10) + t;
    uint32_t bits = rbits(K.kn0, K.kn1, jb + (uint32_t)s);
    uint32_t si = (bits >> 9) + (((cov[s >> 5] >> (s & 31)) & 1u) << 23);
    sr[i] = si;
    atomicAdd(&hist[si >> 12], 1u);
  }
  __syncthreads();

  // ---- phase 3: level-1 select via wave-shuffle suffix scan ----
  {
    uint32_t mysum = 0;
#pragma unroll
    for (int i = 0; i < 4; ++i) mysum += hist[t * 4 + i];
    uint32_t v = mysum;
#pragma unroll
    for (int off = 1; off < 64; off <<= 1) {
      uint32_t n = __shfl_down(v, off, 64);
      if (lane + off < 64) v += n;
    }
    if (lane == 0) wsum[wid] = v;   // wave totals
    __syncthreads();
    if (t < 16) {
      uint32_t w = wsum[t];
#pragma unroll
      for (int off = 1; off < 16; off <<= 1) {
        uint32_t n = __shfl_down(w, off, 64);
        if (t + off < 16) w += n;
      }
      ssum[t] = w;                  // inclusive suffix over wave totals
    }
    __syncthreads();
    uint32_t mine = v + (ssum[wid] - wsum[wid]);   // sum of chunks >= mine
    uint32_t above = mine - mysum;                  // strictly above my chunk
    if (above < TGT && TGT <= mine) {
      uint32_t run = above;
      for (int hb = t * 4 + 3; hb >= t * 4; --hb) {
        uint32_t c = hist[hb];
        if (run + c >= TGT) { sH = (uint32_t)hb; sA = run; break; }
        run += c;
      }
    }
  }
  __syncthreads();
  uint32_t H = sH;
  uint32_t targetB = TGT - sA;

  for (int i = t; i < 4096; i += 1024) hist[i] = 0u;
  __syncthreads();

  // ---- phase 4: level-2 histogram from registers ----
#pragma unroll
  for (int i = 0; i < 16; ++i) {
    uint32_t si = sr[i];
    if ((si >> 12) == H) atomicAdd(&hist[si & 4095u], 1u);
  }
  __syncthreads();
  {
    uint32_t mysum = 0;
#pragma unroll
    for (int i = 0; i < 4; ++i) mysum += hist[t * 4 + i];
    uint32_t v = mysum;
#pragma unroll
    for (int off = 1; off < 64; off <<= 1) {
      uint32_t n = __shfl_down(v, off, 64);
      if (lane + off < 64) v += n;
    }
    if (lane == 0) wsum[wid] = v;
    __syncthreads();
    if (t < 16) {
      uint32_t w = wsum[t];
#pragma unroll
      for (int off = 1; off < 16; off <<= 1) {
        uint32_t n = __shfl_down(w, off, 64);
        if (t + off < 16) w += n;
      }
      ssum[t] = w;
    }
    __syncthreads();
    uint32_t mine = v + (ssum[wid] - wsum[wid]);
    uint32_t above = mine - mysum;
    if (above < targetB && targetB <= mine) {
      uint32_t run = above;
      for (int lb = t * 4 + 3; lb >= t * 4; --lb) {
        uint32_t c = hist[lb];
        if (run + c >= targetB) {
          sT = (H << 12) | (uint32_t)lb;
          sN = targetB - run;   // # ties at T accepted (lowest indices first)
          break;
        }
        run += c;
      }
    }
  }
  __syncthreads();
  uint32_t T = sT, need = sN;

  // ---- phase 5: emit bits via ballot; rank ties by index ----
#pragma unroll
  for (int i = 0; i < 16; ++i) {
    int s = (i << 10) + t;
    uint32_t si = sr[i];
    unsigned long long bal = __ballot(si > T);
    if (si == T) {
      int idx = atomicAdd(&tieCnt, 1);
      if (idx < 256) tielist[idx] = s;
    }
    if (lane == 0)       fm[s >> 5] = (uint32_t)bal;
    else if (lane == 32) fm[s >> 5] = (uint32_t)(bal >> 32);
  }
  __syncthreads();
  int tc = tieCnt < 256 ? tieCnt : 256;
  if (t < tc) {
    int s = tielist[t];
    uint32_t rank = 0;
    for (int j = 0; j < tc; ++j) rank += (tielist[j] < s) ? 1u : 0u;
    if (rank < need) atomicOr(&fm[s >> 5], 1u << (s & 31));
  }
  __syncthreads();

  // ---------------- masked copy of this block's half-row ----------------
  // NOTE: reference masks only valid (non-NaN ch0) positions; token writes are
  // suppressed where feat ch0 is NaN. With the select-form below, a masked
  // NaN-ch0 position keeps its original values because we check ch0 from the
  // loaded vector itself (ch0 is elem 0 of a c0==0 float4). We must replicate
  // "valid = !isnan(ch0)" exactly: compute validity per POSITION from ch0.
  // ch0 of position p lives at float index 6p -> inside the c0==0 float4 (elem
  // 0) or the c0==4 float4 (elem 2, as p0+1's ch0). For each float4 we need
  // validity of p0 and p0+1; p's ch0 is at global float 6p, which may be in a
  // DIFFERENT float4 than the one being processed. Loading it separately would
  // double reads; instead exploit: 3 consecutive float4s (q%3==0,1,2) cover 2
  // whole positions' worth... Simpler exact approach: per float4, for each of
  // the (at most 2) positions involved, load ch0 directly via a scalar read
  // feat[row*ROWF + 6*p]. These are L1/L2 hits (same lines just streamed) and
  // only issued for MASKED positions (~15%), predicated.
  {
    const float t0 = tok[0], t1 = tok[1], t2 = tok[2];
    const float t3 = tok[3], t4 = tok[4], t5 = tok[5];
    const size_t rowBase4 = (size_t)b * ROWF4 + (size_t)h * HALF4;
    const float* rowf = feat + (size_t)b * ROWF;      // for ch0 validity probes
    const f32x4* rf4 = (const f32x4*)feat + rowBase4;
    f32x4* ro4 = (f32x4*)out + rowBase4;
    const int qbase = h * HALF4;                      // f4 index within row

#pragma unroll
    for (int batch = 0; batch < 3; ++batch) {
      f32x4 v0, v1, v2, v3;
      const int q0 = t + (batch * 4) * 1024;
      v0 = rf4[q0];
      v1 = rf4[q0 + 1024];
      v2 = rf4[q0 + 2048];
      v3 = rf4[q0 + 3072];

      f32x4 vv[4] = {v0, v1, v2, v3};
#pragma unroll
      for (int j = 0; j < 4; ++j) {
        const int qrow = qbase + q0 + j * 1024;       // f4 index within row
        const int e = qrow * 4;                       // float index within row
        const int p0 = e / 6;                         // position (magic mul)
        const int c0 = e - p0 * 6;                    // 0, 2, or 4
        const int p1 = (p0 + 1 < SEQ) ? p0 + 1 : SEQ - 1;
        const uint32_t w0 = fm[p0 >> 5];
        const uint32_t w1 = fm[p1 >> 5];
        bool m0 = (w0 >> (p0 & 31)) & 1u;
        bool m1 = (w1 >> (p1 & 31)) & 1u;
        // validity: !isnan(ch0 of that position). Only matters when masked.
        if (m0) {
          float c0v = rowf[p0 * 6];
          m0 = !(c0v != c0v);
        }
        if (m1) {
          float c1v = rowf[p1 * 6];
          m1 = !(c1v != c1v);
        }
        const bool is0 = (c0 == 0), is2 = (c0 == 2);
        const float a0 = is0 ? t0 : (is2 ? t2 : t4);
        const float a1 = is0 ? t1 : (is2 ? t3 : t5);
        const float a2 = is0 ? t2 : (is2 ? t4 : t0);
        const float a3 = is0 ? t3 : (is2 ? t5 : t1);
        const bool u01 = m0;                          // elems 0,1 always pos p0
        const bool u23 = (!is0 && !is2) ? m1 : m0;    // c0==4 -> elems 2,3 are p0+1
        f32x4 v = vv[j];
        v.x = u01 ? a0 : v.x;
        v.y = u01 ? a1 : v.y;
        v.z = u23 ? a2 : v.z;
        v.w = u23 ? a3 : v.w;
        vv[j] = v;
      }
      __builtin_nontemporal_store(vv[0], &ro4[q0]);
      __builtin_nontemporal_store(vv[1], &ro4[q0 + 1024]);
      __builtin_nontemporal_store(vv[2], &ro4[q0 + 2048]);
      __builtin_nontemporal_store(vv[3], &ro4[q0 + 3072]);
    }
  }
}

extern "C" void kernel_launch(void* const* d_in, const int* in_sizes, int n_in,
                              void* d_out, int out_size, void* d_ws, size_t ws_size,
                              hipStream_t stream) {
  const float* feat = (const float*)d_in[0];
  const float* tok = (const float*)d_in[1];
  float* out = (float*)d_out;

  // ---- host-side key derivation (partitionable threefry) ----
  // key(1234) -> (0, 1234); split(key,3) foldlike: child i = tf(key, (0, i))
  uint32_t klen0, klen1, kst0, kst1, kn0, kn1;
  tf2x32(0u, 1234u, 0u, 0u, klen0, klen1);   // k_len
  tf2x32(0u, 1234u, 0u, 1u, kst0, kst1);     // k_start
  tf2x32(0u, 1234u, 0u, 2u, kn0, kn1);       // k_noise
  uint32_t lh0, lh1, ll0, ll1;
  tf2x32(klen0, klen1, 0u, 0u, lh0, lh1);    // unused (span=16 pow2)
  tf2x32(klen0, klen1, 0u, 1u, ll0, ll1);
  (void)lh0; (void)lh1;
  uint32_t sh0, sh1, sl0, sl1;
  tf2x32(kst0, kst1, 0u, 0u, sh0, sh1);
  tf2x32(kst0, kst1, 0u, 1u, sl0, sl1);
  Keys K{ ll0, ll1, sh0, sh1, sl0, sl1, kn0, kn1 };

  // Single ordinary launch: 2 blocks per row, no workspace dependency.
  hipLaunchKernelGGL(rowpair_kernel, dim3(2 * NB), dim3(1024), 0, stream,
                     feat, tok, out, K);
}